// Round 6
// baseline (536.440 us; speedup 1.0000x reference)
//
#include <hip/hip_runtime.h>

typedef unsigned short u16;
typedef unsigned int u32;
typedef __bf16 bf16x8 __attribute__((ext_vector_type(8)));
typedef __bf16 bf16x4 __attribute__((ext_vector_type(4)));
typedef float f32x4 __attribute__((ext_vector_type(4)));
typedef float f32x16 __attribute__((ext_vector_type(16)));

#define MFMA16(a, b, c) __builtin_amdgcn_mfma_f32_16x16x32_bf16(a, b, c, 0, 0, 0)
#define MFMA32(a, b, c) __builtin_amdgcn_mfma_f32_32x32x16_bf16(a, b, c, 0, 0, 0)

__device__ __forceinline__ u16 f2bf(float f) {
  u32 u = __float_as_uint(f);
  u += 0x7FFFu + ((u >> 16) & 1u);
  return (u16)(u >> 16);
}
__device__ __forceinline__ float bf2f(u16 h) {
  return __uint_as_float(((u32)h) << 16);
}

__device__ __forceinline__ void gload_lds16(const u16* g, u16* l) {
  __builtin_amdgcn_global_load_lds((__attribute__((address_space(1))) void*)g,
                                   (__attribute__((address_space(3))) void*)l,
                                   16, 0, 0);
}

// ---------------------------------------------------------------------------
// fp32 -> bf16 elementwise convert (x). 4 elems/thread.
// ---------------------------------------------------------------------------
__global__ __launch_bounds__(256) void cvt_x(const float* __restrict__ in,
                                             u16* __restrict__ out) {
  int i = (blockIdx.x * 256 + threadIdx.x) * 4;
  float4 v = *(const float4*)&in[i];
  ushort4 o;
  o.x = f2bf(v.x);
  o.y = f2bf(v.y);
  o.z = f2bf(v.z);
  o.w = f2bf(v.w);
  *(ushort4*)&out[i] = o;
}

// ---------------------------------------------------------------------------
// Transpose + convert: in[R][C] fp32 (row stride ldin) -> out[C][R] bf16
// ---------------------------------------------------------------------------
__global__ __launch_bounds__(256) void tbf_f2b(const float* __restrict__ in,
                                               u16* __restrict__ out,
                                               int ldin, int ldout) {
  __shared__ float tile[64][65];
  const int t = threadIdx.x;
  const int c4 = t & 15;
  const int rb = t >> 4;
  const int r0 = blockIdx.y * 64;
  const int c0 = blockIdx.x * 64;
#pragma unroll
  for (int p = 0; p < 4; p++) {
    int r = p * 16 + rb;
    float4 v = *(const float4*)&in[(size_t)(r0 + r) * ldin + c0 + c4 * 4];
    tile[r][c4 * 4 + 0] = v.x;
    tile[r][c4 * 4 + 1] = v.y;
    tile[r][c4 * 4 + 2] = v.z;
    tile[r][c4 * 4 + 3] = v.w;
  }
  __syncthreads();
#pragma unroll
  for (int p = 0; p < 4; p++) {
    int oc = p * 16 + rb;
    ushort4 v;
    v.x = f2bf(tile[c4 * 4 + 0][oc]);
    v.y = f2bf(tile[c4 * 4 + 1][oc]);
    v.z = f2bf(tile[c4 * 4 + 2][oc]);
    v.w = f2bf(tile[c4 * 4 + 3][oc]);
    *(ushort4*)&out[(size_t)(c0 + oc) * ldout + r0 + c4 * 4] = v;
  }
}

// ---------------------------------------------------------------------------
// bf16 transpose: in[R][C] -> out[C][R]
// ---------------------------------------------------------------------------
__global__ __launch_bounds__(256) void tbf_b(const u16* __restrict__ in,
                                             u16* __restrict__ out,
                                             int ldin, int ldout) {
  __shared__ u16 tile[64][68];
  const int t = threadIdx.x;
  const int c4 = t & 15;
  const int rb = t >> 4;
  const int r0 = blockIdx.y * 64;
  const int c0 = blockIdx.x * 64;
#pragma unroll
  for (int p = 0; p < 4; p++) {
    int r = p * 16 + rb;
    ushort4 v = *(const ushort4*)&in[(size_t)(r0 + r) * ldin + c0 + c4 * 4];
    *(ushort4*)&tile[r][c4 * 4] = v;
  }
  __syncthreads();
#pragma unroll
  for (int p = 0; p < 4; p++) {
    int oc = p * 16 + rb;
    ushort4 v;
    v.x = tile[c4 * 4 + 0][oc];
    v.y = tile[c4 * 4 + 1][oc];
    v.z = tile[c4 * 4 + 2][oc];
    v.w = tile[c4 * 4 + 3][oc];
    *(ushort4*)&out[(size_t)(c0 + oc) * ldout + r0 + c4 * 4] = v;
  }
}

// ---------------------------------------------------------------------------
// 32x32x16-MFMA bf16 GEMM: C[M][N] = A[M][K] @ B^T, B stored [N][K].
// Rationale (r5 post-mortem): the 16x16 kernels were LDS-read-issue bound
// (176 ds_read_b128/K-tile/CU ~ 2112 cyc > MFMA 1863 cyc; schedule changes
// r3-r5 all landed 123-160us). 32x32x16 delivers 2x FLOP per operand byte:
// 4 waves (2M x 2N), per-wave 128x96 (QKV) / 128x64 (proj) -> per-CU per
// K-tile reads drop to 112 instrs (~1344 cyc) while MFMA is ~1623 cyc at the
// faster 32x32 rate -- compute-dominant for the first time. 1 wave/SIMD:
// latency hiding via single-wave ILP (compiler-pipelined unrolled body,
// proven in r1); VGPR budget 512 at 1 wave/EU holds acc(192)+operands.
// Chassis = r1 (proven): BM=256, BK=64, 2-dbuf LDS, stage-at-head,
// counted vmcnt(LL) (t+1's loads stay in flight across the barrier),
// 2 barriers/K-tile. LDS rows 64 cols (128B); 16B-chunk swizzle
// h ^= (r&7)^((r>>3)&3): every 8-lane group of a 32-row frag read covers
// all 8 chunk slots -> conflict-free. Swizzle on GLOBAL source addr
// (gload_lds writes lane-linear) + read addr (involution, rule #21).
// Grid = 256 blocks exactly; id&7 -> M-panel (2MB A-panel per XCD L2).
// MFMA frag layout 32x32x16: A/B lane l: row/col = l&31, k = (l>>5)*8+e;
// C/D: col = l&31, row = (reg&3) + 8*(reg>>2) + 4*(l>>5)  [m74/m101].
// ---------------------------------------------------------------------------
template <int BN, int F32OUT>
__global__ __launch_bounds__(256, 1) void gemw(const u16* __restrict__ A,
                                               const u16* __restrict__ B,
                                               void* __restrict__ Cv,
                                               int K, int ldc) {
  constexpr int NC = BN / 64;  // 32-wide B frags per wave: 3 or 2
  constexpr int UA = 8;        // A stage units (256thr x 16B = 32 rows each)
  constexpr int UB = BN / 32;  // B stage units: 6 or 4
  constexpr int LL = UA + UB;  // loads/thread/tile: 14 or 12
  __shared__ __attribute__((aligned(16))) u16 As[2][256 * 64];
  __shared__ __attribute__((aligned(16))) u16 Bs[2][BN * 64];
  const int tid = threadIdx.x;
  const int wave = tid >> 6;
  const int lane = tid & 63;
  const int l32 = lane & 31;
  const int hk = lane >> 5;  // k-half
  const int wm = wave >> 1;  // 0..1 : 128-row slice
  const int wc = wave & 1;   // 0..1 : (BN/2)-col slice
  const int id = blockIdx.x;      // 256 blocks
  const int bm = (id & 7) * 256;  // XCD k -> M panel k
  const int bn0 = (id >> 3) * BN;

  // staging source pointers (pre-swizzled; involution with read side)
  const u16* srcA[UA];
#pragma unroll
  for (int m = 0; m < UA; m++) {
    int c = m * 256 + tid;  // 16B chunk: row c>>3, slot c&7
    int r = c >> 3;
    int hl = (c & 7) ^ (r & 7) ^ ((r >> 3) & 3);
    srcA[m] = A + (size_t)(bm + r) * K + hl * 8;
  }
  const u16* srcB[UB];
#pragma unroll
  for (int m = 0; m < UB; m++) {
    int c = m * 256 + tid;
    int r = c >> 3;
    int hl = (c & 7) ^ (r & 7) ^ ((r >> 3) & 3);
    srcB[m] = B + (size_t)(bn0 + r) * K + hl * 8;
  }

  f32x16 acc[4][NC];
#pragma unroll
  for (int i = 0; i < 4; i++)
#pragma unroll
    for (int j = 0; j < NC; j++)
#pragma unroll
      for (int e = 0; e < 16; e++) acc[i][j][e] = 0.f;

  auto stage = [&](int ko, int buf) {
#pragma unroll
    for (int m = 0; m < UA; m++)
      gload_lds16(srcA[m] + ko, &As[buf][(m * 256 + tid) * 8]);
#pragma unroll
    for (int m = 0; m < UB; m++)
      gload_lds16(srcB[m] + ko, &Bs[buf][(m * 256 + tid) * 8]);
  };

  const int NT = K >> 6;
  stage(0, 0);
  for (int t = 0; t < NT; ++t) {
    // head: issue tile t+1, then wait only tile t's LL loads (counted)
    if (t + 1 < NT) {
      stage((t + 1) << 6, (t + 1) & 1);
      if constexpr (LL == 14)
        asm volatile("s_waitcnt vmcnt(14)" ::: "memory");
      else
        asm volatile("s_waitcnt vmcnt(12)" ::: "memory");
    } else {
      asm volatile("s_waitcnt vmcnt(0)" ::: "memory");
    }
    __builtin_amdgcn_sched_barrier(0);
    __builtin_amdgcn_s_barrier();
    __builtin_amdgcn_sched_barrier(0);

    const u16* as = &As[t & 1][0];
    const u16* bs = &Bs[t & 1][0];
#pragma unroll
    for (int ks = 0; ks < 4; ks++) {
      bf16x8 aF[4], bF[NC];
#pragma unroll
      for (int i = 0; i < 4; i++) {
        int r = wm * 128 + i * 32 + l32;
        int pc = (ks * 2 + hk) ^ (r & 7) ^ ((r >> 3) & 3);
        aF[i] = *(const bf16x8*)&as[r * 64 + pc * 8];
      }
#pragma unroll
      for (int j = 0; j < NC; j++) {
        int r = wc * (NC * 32) + j * 32 + l32;
        int pc = (ks * 2 + hk) ^ (r & 7) ^ ((r >> 3) & 3);
        bF[j] = *(const bf16x8*)&bs[r * 64 + pc * 8];
      }
      __builtin_amdgcn_s_setprio(1);
#pragma unroll
      for (int i = 0; i < 4; i++)
#pragma unroll
        for (int j = 0; j < NC; j++)
          acc[i][j] = MFMA32(aF[i], bF[j], acc[i][j]);
      __builtin_amdgcn_s_setprio(0);
    }
    __builtin_amdgcn_sched_barrier(0);
    __builtin_amdgcn_s_barrier();  // all waves done with buf[t&1]; next
    __builtin_amdgcn_sched_barrier(0);  // stage may overwrite buf[(t+1)&1]
  }

  const int crow0 = bm + wm * 128;
  const int ccol0 = bn0 + wc * (NC * 32);
  if constexpr (F32OUT) {
    float* Cp = (float*)Cv;
#pragma unroll
    for (int i = 0; i < 4; i++)
#pragma unroll
      for (int j = 0; j < NC; j++)
#pragma unroll
        for (int reg = 0; reg < 16; reg++) {
          int row = crow0 + i * 32 + (reg & 3) + 8 * (reg >> 2) + 4 * hk;
          int col = ccol0 + j * 32 + l32;
          Cp[(size_t)row * ldc + col] = acc[i][j][reg];
        }
  } else {
    u16* Cp = (u16*)Cv;
#pragma unroll
    for (int i = 0; i < 4; i++)
#pragma unroll
      for (int j = 0; j < NC; j++)
#pragma unroll
        for (int reg = 0; reg < 16; reg++) {
          int row = crow0 + i * 32 + (reg & 3) + 8 * (reg >> 2) + 4 * hk;
          int col = ccol0 + j * 32 + l32;
          Cp[(size_t)row * ldc + col] = f2bf(acc[i][j][reg]);
        }
  }
}

// ---------------------------------------------------------------------------
// In-place RoPE on Q (cols 0..4095) and K (cols 4096..5119) of qkv[2048][6144].
// ---------------------------------------------------------------------------
__global__ __launch_bounds__(256) void rope_k(u16* __restrict__ qkv,
                                              const float* __restrict__ fc,
                                              const float* __restrict__ fs) {
  int idx = blockIdx.x * 256 + threadIdx.x;
  int j = idx & 63;
  int rem = idx >> 6;
  int head = rem % 40;
  int s = rem / 40;
  float c = fc[s * 64 + j];
  float sn = fs[s * 64 + j];
  int col = (head < 32) ? (head * 128 + 2 * j) : (4096 + (head - 32) * 128 + 2 * j);
  u32* p = (u32*)&qkv[(size_t)s * 6144 + col];
  u32 v = *p;
  float e = bf2f((u16)(v & 0xFFFFu));
  float o = bf2f((u16)(v >> 16));
  float re = e * c - o * sn;
  float ro = e * sn + o * c;
  *p = (u32)f2bf(re) | ((u32)f2bf(ro) << 16);
}

// ---------------------------------------------------------------------------
// Sliding-window causal GQA attention, LDS-staged K/V, unshifted softmax.
// grid = (32 heads, 16 q-blocks of 128), block = 256 (4 waves, 32 q/wave).
// ---------------------------------------------------------------------------
__global__ __launch_bounds__(256) void attn_k(const u16* __restrict__ qkv,
                                              const u16* __restrict__ vt,
                                              u16* __restrict__ outb) {
  __shared__ __attribute__((aligned(16))) u16 Kb[2][32 * 128];
  __shared__ __attribute__((aligned(16))) u16 Vb[2][128 * 32];
  __shared__ __attribute__((aligned(16))) u16 plds[4][32 * 36];
  const int h = blockIdx.x;
  const int q0 = blockIdx.y * 128;
  const int t = threadIdx.x;
  const int wave = t >> 6;
  const int lane = t & 63;
  const int l16 = lane & 15;
  const int quad = lane >> 4;
  const int hkv = h >> 2;
  const int qw = q0 + wave * 32;
  u16* myp = &plds[wave][0];

  // Q fragments: 2 sets of 16 rows
  bf16x8 qa[2][4];
#pragma unroll
  for (int i = 0; i < 2; i++)
#pragma unroll
    for (int kc = 0; kc < 4; kc++)
      qa[i][kc] = *(const bf16x8*)&qkv[(size_t)(qw + i * 16 + l16) * 6144 +
                                       h * 128 + kc * 32 + quad * 8];

  f32x4 o[2][8];
#pragma unroll
  for (int i = 0; i < 2; i++)
#pragma unroll
    for (int d = 0; d < 8; d++) o[i][d] = (f32x4){0.f, 0.f, 0.f, 0.f};
  float lloc[2][4] = {{0.f, 0.f, 0.f, 0.f}, {0.f, 0.f, 0.f, 0.f}};

  const int kb_start = (q0 - 1023 > 0 ? q0 - 1023 : 0) & ~31;
  const int kb_last = q0 + 96;  // (q0+127) & ~31
  const float sc = 0.08838834764831845f;  // 1/sqrt(128)

  const int kr0 = t >> 4, kc0s = t & 15;
  const int kr1 = (256 + t) >> 4, kc1s = t & 15;
  const int vr0 = t >> 2, vc0s = t & 3;
  const int vr1 = (256 + t) >> 2, vc1s = t & 3;
  const u16* kg = qkv + 4096 + hkv * 128;
  const u16* vg = vt + (size_t)hkv * 128 * 2048;

#define STAGE(kb_, nb_)                                                        \
  do {                                                                         \
    int kb__ = (kb_);                                                          \
    gload_lds16(&kg[(size_t)(kb__ + kr0) * 6144 + (kc0s ^ (kr0 & 15)) * 8],    \
                &Kb[nb_][t * 8]);                                              \
    gload_lds16(&kg[(size_t)(kb__ + kr1) * 6144 + (kc1s ^ (kr1 & 15)) * 8],    \
                &Kb[nb_][2048 + t * 8]);                                       \
    gload_lds16(&vg[(size_t)vr0 * 2048 + kb__ + (vc0s ^ (vr0 & 3)) * 8],       \
                &Vb[nb_][t * 8]);                                              \
    gload_lds16(&vg[(size_t)vr1 * 2048 + kb__ + (vc1s ^ (vr1 & 3)) * 8],       \
                &Vb[nb_][2048 + t * 8]);                                       \
  } while (0)

  STAGE(kb_start, 0);
  int cur = 0;

  for (int kb = kb_start; kb <= kb_last; kb += 32) {
    __syncthreads();  // drains vmcnt: buf[cur] staged; all waves done with prev
    if (kb + 32 <= kb_last) STAGE(kb + 32, cur ^ 1);
    const u16* kcur = &Kb[cur][0];
    const u16* vcur = &Vb[cur][0];

    // ---- QK^T: 32q x 32k ----
    f32x4 s0[2] = {(f32x4){0.f, 0.f, 0.f, 0.f}, (f32x4){0.f, 0.f, 0.f, 0.f}};
    f32x4 s1[2] = {(f32x4){0.f, 0.f, 0.f, 0.f}, (f32x4){0.f, 0.f, 0.f, 0.f}};
#pragma unroll
    for (int kc = 0; kc < 4; kc++) {
      int ch = ((kc * 4 + quad) ^ l16) * 8;
      bf16x8 b0 = *(const bf16x8*)&kcur[l16 * 128 + ch];
      bf16x8 b1 = *(const bf16x8*)&kcur[(l16 + 16) * 128 + ch];
      s0[0] = MFMA16(qa[0][kc], b0, s0[0]);
      s1[0] = MFMA16(qa[0][kc], b1, s1[0]);
      s0[1] = MFMA16(qa[1][kc], b0, s0[1]);
      s1[1] = MFMA16(qa[1][kc], b1, s1[1]);
    }

    // ---- unshifted softmax numerator + pack ----
    float p0[2][4], p1[2][4];
    bool fast = (kb + 31 <= qw) && (qw + 31 - kb <= 1023);
    if (fast) {
#pragma unroll
      for (int i = 0; i < 2; i++)
#pragma unroll
        for (int r = 0; r < 4; r++) {
          p0[i][r] = __expf(s0[i][r] * sc);
          p1[i][r] = __expf(s1[i][r] * sc);
        }
    } else {
#pragma unroll
      for (int i = 0; i < 2; i++)
#pragma unroll
        for (int r = 0; r < 4; r++) {
          int row = qw + i * 16 + quad * 4 + r;
          int col0 = kb + l16;
          int col1 = col0 + 16;
          bool v0 = (col0 <= row) && (row - col0 < 1024);
          bool v1 = (col1 <= row) && (row - col1 < 1024);
          p0[i][r] = v0 ? __expf(s0[i][r] * sc) : 0.f;
          p1[i][r] = v1 ? __expf(s1[i][r] * sc) : 0.f;
        }
    }
#pragma unroll
    for (int i = 0; i < 2; i++)
#pragma unroll
      for (int r = 0; r < 4; r++) {
        lloc[i][r] += p0[i][r] + p1[i][r];
        myp[(i * 16 + quad * 4 + r) * 36 + l16] = f2bf(p0[i][r]);
        myp[(i * 16 + quad * 4 + r) * 36 + l16 + 16] = f2bf(p1[i][r]);
      }
    asm volatile("s_waitcnt lgkmcnt(0)" ::: "memory");
    bf16x8 pa[2];
#pragma unroll
    for (int i = 0; i < 2; i++) {
      bf16x4 lo = *(const bf16x4*)&myp[(i * 16 + l16) * 36 + quad * 8];
      bf16x4 hi = *(const bf16x4*)&myp[(i * 16 + l16) * 36 + quad * 8 + 4];
#pragma unroll
      for (int j = 0; j < 4; j++) {
        pa[i][j] = lo[j];
        pa[i][j + 4] = hi[j];
      }
    }
    // ---- PV: V fragments read once, shared by both A-frag sets ----
#pragma unroll
    for (int d = 0; d < 8; d++) {
      int rv = l16 + 16 * d;
      bf16x8 vb = *(const bf16x8*)&vcur[rv * 32 + ((quad ^ (l16 & 3)) * 8)];
      o[0][d] = MFMA16(pa[0], vb, o[0][d]);
      o[1][d] = MFMA16(pa[1], vb, o[1][d]);
    }
    cur ^= 1;
  }

  // ---- final row-sum reduce + divide + store ----
#pragma unroll
  for (int i = 0; i < 2; i++) {
    float inv[4];
#pragma unroll
    for (int r = 0; r < 4; r++) {
      float l = lloc[i][r];
#pragma unroll
      for (int m = 8; m >= 1; m >>= 1) l += __shfl_xor(l, m, 64);
      inv[r] = 1.0f / l;
    }
#pragma unroll
    for (int d = 0; d < 8; d++)
#pragma unroll
      for (int r = 0; r < 4; r++) {
        int row = qw + i * 16 + quad * 4 + r;
        outb[(size_t)row * 4096 + h * 128 + d * 16 + l16] =
            f2bf(o[i][d][r] * inv[r]);
      }
  }
#undef STAGE
}

// ---------------------------------------------------------------------------
// Workspace layout (bytes):
//   0         : xb    [2048][4096] bf16 (16777216)
//   16777216  : wqkvT [6144][4096] bf16 (50331648)  (wq rows 0..4095,
//               wk rows 4096..5119, wv rows 5120..6143; contiguous)
//               -- reused for woT [4096][4096] after GEMM1
//   67108864  : qkvb  [2048][6144] bf16 (25165824)
//   92274688  : vtb   [1024][2048] bf16 ( 4194304)
//   96468992  : aout  [2048][4096] bf16 (16777216)
// ---------------------------------------------------------------------------
extern "C" void kernel_launch(void* const* d_in, const int* in_sizes, int n_in,
                              void* d_out, int out_size, void* d_ws, size_t ws_size,
                              hipStream_t stream) {
  const float* x = (const float*)d_in[0];
  const float* fc = (const float*)d_in[1];
  const float* fs = (const float*)d_in[2];
  // d_in[3] = mask (unused; recomputed analytically)
  const float* wq = (const float*)d_in[4];
  const float* wk = (const float*)d_in[5];
  const float* wv = (const float*)d_in[6];
  const float* wo = (const float*)d_in[7];
  float* outp = (float*)d_out;
  char* ws = (char*)d_ws;
  u16* xb = (u16*)(ws);
  u16* wqkvT = (u16*)(ws + 16777216);
  u16* qkvb = (u16*)(ws + 67108864);
  u16* vtb = (u16*)(ws + 92274688);
  u16* aout = (u16*)(ws + 96468992);

  cvt_x<<<8192, 256, 0, stream>>>(x, xb);
  tbf_f2b<<<dim3(64, 64), 256, 0, stream>>>(wq, wqkvT, 4096, 4096);
  tbf_f2b<<<dim3(16, 64), 256, 0, stream>>>(wk, wqkvT + (size_t)4096 * 4096,
                                            1024, 4096);
  tbf_f2b<<<dim3(16, 64), 256, 0, stream>>>(wv, wqkvT + (size_t)5120 * 4096,
                                            1024, 4096);
  gemw<192, 0><<<256, 256, 0, stream>>>(xb, wqkvT, qkvb, 4096, 6144);
  rope_k<<<20480, 256, 0, stream>>>(qkvb, fc, fs);
  tbf_b<<<dim3(16, 32), 256, 0, stream>>>(qkvb + 5120, vtb, 6144, 2048);
  tbf_f2b<<<dim3(64, 64), 256, 0, stream>>>(wo, wqkvT, 4096, 4096);
  attn_k<<<dim3(32, 16), 256, 0, stream>>>(qkvb, vtb, aout);
  gemw<128, 1><<<256, 256, 0, stream>>>(aout, wqkvT, outp, 4096, 4096);
}

// Round 7
// 478.392 us; speedup vs baseline: 1.1213x; 1.1213x over previous
//
#include <hip/hip_runtime.h>

typedef unsigned short u16;
typedef unsigned int u32;
typedef __bf16 bf16x8 __attribute__((ext_vector_type(8)));
typedef __bf16 bf16x4 __attribute__((ext_vector_type(4)));
typedef float f32x4 __attribute__((ext_vector_type(4)));

#define MFMA16(a, b, c) __builtin_amdgcn_mfma_f32_16x16x32_bf16(a, b, c, 0, 0, 0)

__device__ __forceinline__ u16 f2bf(float f) {
  u32 u = __float_as_uint(f);
  u += 0x7FFFu + ((u >> 16) & 1u);
  return (u16)(u >> 16);
}
__device__ __forceinline__ float bf2f(u16 h) {
  return __uint_as_float(((u32)h) << 16);
}

__device__ __forceinline__ void gload_lds16(const u16* g, u16* l) {
  __builtin_amdgcn_global_load_lds((__attribute__((address_space(1))) void*)g,
                                   (__attribute__((address_space(3))) void*)l,
                                   16, 0, 0);
}

// ---------------------------------------------------------------------------
// fp32 -> bf16 elementwise convert (x). 4 elems/thread.
// ---------------------------------------------------------------------------
__global__ __launch_bounds__(256) void cvt_x(const float* __restrict__ in,
                                             u16* __restrict__ out) {
  int i = (blockIdx.x * 256 + threadIdx.x) * 4;
  float4 v = *(const float4*)&in[i];
  ushort4 o;
  o.x = f2bf(v.x);
  o.y = f2bf(v.y);
  o.z = f2bf(v.z);
  o.w = f2bf(v.w);
  *(ushort4*)&out[i] = o;
}

// ---------------------------------------------------------------------------
// Transpose + convert: in[R][C] fp32 (row stride ldin) -> out[C][R] bf16
// ---------------------------------------------------------------------------
__global__ __launch_bounds__(256) void tbf_f2b(const float* __restrict__ in,
                                               u16* __restrict__ out,
                                               int ldin, int ldout) {
  __shared__ float tile[64][65];
  const int t = threadIdx.x;
  const int c4 = t & 15;
  const int rb = t >> 4;
  const int r0 = blockIdx.y * 64;
  const int c0 = blockIdx.x * 64;
#pragma unroll
  for (int p = 0; p < 4; p++) {
    int r = p * 16 + rb;
    float4 v = *(const float4*)&in[(size_t)(r0 + r) * ldin + c0 + c4 * 4];
    tile[r][c4 * 4 + 0] = v.x;
    tile[r][c4 * 4 + 1] = v.y;
    tile[r][c4 * 4 + 2] = v.z;
    tile[r][c4 * 4 + 3] = v.w;
  }
  __syncthreads();
#pragma unroll
  for (int p = 0; p < 4; p++) {
    int oc = p * 16 + rb;
    ushort4 v;
    v.x = f2bf(tile[c4 * 4 + 0][oc]);
    v.y = f2bf(tile[c4 * 4 + 1][oc]);
    v.z = f2bf(tile[c4 * 4 + 2][oc]);
    v.w = f2bf(tile[c4 * 4 + 3][oc]);
    *(ushort4*)&out[(size_t)(c0 + oc) * ldout + r0 + c4 * 4] = v;
  }
}

// ---------------------------------------------------------------------------
// bf16 transpose: in[R][C] -> out[C][R]
// ---------------------------------------------------------------------------
__global__ __launch_bounds__(256) void tbf_b(const u16* __restrict__ in,
                                             u16* __restrict__ out,
                                             int ldin, int ldout) {
  __shared__ u16 tile[64][68];
  const int t = threadIdx.x;
  const int c4 = t & 15;
  const int rb = t >> 4;
  const int r0 = blockIdx.y * 64;
  const int c0 = blockIdx.x * 64;
#pragma unroll
  for (int p = 0; p < 4; p++) {
    int r = p * 16 + rb;
    ushort4 v = *(const ushort4*)&in[(size_t)(r0 + r) * ldin + c0 + c4 * 4];
    *(ushort4*)&tile[r][c4 * 4] = v;
  }
  __syncthreads();
#pragma unroll
  for (int p = 0; p < 4; p++) {
    int oc = p * 16 + rb;
    ushort4 v;
    v.x = tile[c4 * 4 + 0][oc];
    v.y = tile[c4 * 4 + 1][oc];
    v.z = tile[c4 * 4 + 2][oc];
    v.w = tile[c4 * 4 + 3][oc];
    *(ushort4*)&out[(size_t)(c0 + oc) * ldout + r0 + c4 * 4] = v;
  }
}

// ---------------------------------------------------------------------------
// m201-style 8-phase bf16 GEMM (r5 best-known: 123us QKV, 0 bank conflicts).
// See r5 notes: BM=256, BK=64, 8 waves (2M x 4N), 2-dbuf LDS, phases with
// reads-before-entry-barrier, counted vmcnt once per K-tile.
// ---------------------------------------------------------------------------
template <int BN, int F32OUT>
__global__ __launch_bounds__(512, 2) void gemm8(const u16* __restrict__ A,
                                                const u16* __restrict__ B,
                                                void* __restrict__ Cv,
                                                int K, int ldc) {
  constexpr int NC = BN / 64;  // B frags per wave AND B stage units (3 or 2)
  __shared__ __attribute__((aligned(16))) u16 As[2][256 * 64];
  __shared__ __attribute__((aligned(16))) u16 Bs[2][BN * 64];
  const int tid = threadIdx.x;
  const int wave = tid >> 6;
  const int lane = tid & 63;
  const int l16 = lane & 15;
  const int quad = lane >> 4;
  const int wm = wave >> 2;  // 0..1 : 128-row slice
  const int wc = wave & 3;   // 0..3 : (BN/4)-col slice
  const int id = blockIdx.x;     // 256 blocks
  const int bm = (id & 7) * 256; // XCD k -> M panel k
  const int bn0 = (id >> 3) * BN;

  const u16* srcA[4];
#pragma unroll
  for (int m = 0; m < 4; m++) {
    int c = m * 512 + tid;  // 16B chunk: row c>>3, slot c&7
    int r = c >> 3;
    int hl = (c & 7) ^ (r & 7);
    srcA[m] = A + (size_t)(bm + r) * K + hl * 8;
  }
  const u16* srcB[NC];
#pragma unroll
  for (int m = 0; m < NC; m++) {
    int c = m * 512 + tid;
    int r = c >> 3;
    int hl = (c & 7) ^ (r & 7);
    srcB[m] = B + (size_t)(bn0 + r) * K + hl * 8;
  }

  f32x4 acc[8][NC];
#pragma unroll
  for (int i = 0; i < 8; i++)
#pragma unroll
    for (int j = 0; j < NC; j++) acc[i][j] = (f32x4){0.f, 0.f, 0.f, 0.f};

#define STA(u, koff, buf) \
  gload_lds16(srcA[u] + (koff), &As[buf][((u) * 512 + tid) * 8])
#define STB(u, koff, buf) \
  gload_lds16(srcB[u] + (koff), &Bs[buf][((u) * 512 + tid) * 8])
#define SB __builtin_amdgcn_sched_barrier(0)
#define MID                                          \
  SB;                                                \
  __builtin_amdgcn_s_barrier();                      \
  asm volatile("s_waitcnt lgkmcnt(0)" ::: "memory"); \
  SB
#define END                     \
  SB;                           \
  __builtin_amdgcn_s_barrier(); \
  SB

  bf16x8 aR[2][4], bR0[NC], bR1[NC];
  auto rdA = [&](const u16* s, int mh) {
#pragma unroll
    for (int ks = 0; ks < 2; ks++)
#pragma unroll
      for (int ii = 0; ii < 4; ii++) {
        int row = wm * 128 + mh * 64 + ii * 16 + l16;
        aR[ks][ii] = *(const bf16x8*)
            &s[row * 64 + (((ks * 4 + quad) ^ (row & 7)) << 3)];
      }
  };
  auto rdB = [&](const u16* s, int ks, bf16x8(&bR)[NC]) {
#pragma unroll
    for (int j = 0; j < NC; j++) {
      int row = wc * (NC * 16) + j * 16 + l16;
      bR[j] = *(const bf16x8*)
          &s[row * 64 + (((ks * 4 + quad) ^ (row & 7)) << 3)];
    }
  };
  auto cl = [&](bf16x8(&a4)[4], bf16x8(&bR)[NC], int mh) {
    __builtin_amdgcn_s_setprio(1);
#pragma unroll
    for (int ii = 0; ii < 4; ii++)
#pragma unroll
      for (int j = 0; j < NC; j++)
        acc[mh * 4 + ii][j] = MFMA16(a4[ii], bR[j], acc[mh * 4 + ii][j]);
    __builtin_amdgcn_s_setprio(0);
  };

  // ---- prologue: T0 full (4+NC loads) + T1's B units (NC loads) ----
#pragma unroll
  for (int u = 0; u < 4; u++) STA(u, 0, 0);
#pragma unroll
  for (int u = 0; u < NC; u++) STB(u, 0, 0);
#pragma unroll
  for (int u = 0; u < NC; u++) STB(u, 64, 1);
  if constexpr (NC == 3)
    asm volatile("s_waitcnt vmcnt(3)" ::: "memory");
  else
    asm volatile("s_waitcnt vmcnt(2)" ::: "memory");
  END;

  const int NP = K >> 7;  // pairs of K-tiles
  for (int p = 0; p < NP; ++p) {
    const int kT1 = p * 128 + 64;
    const int kT2 = p * 128 + 128;
    const int kT3 = p * 128 + 192;
    const bool more = (p + 1 < NP);
    const u16* as0 = &As[0][0];
    const u16* bs0 = &Bs[0][0];
    const u16* as1 = &As[1][0];
    const u16* bs1 = &Bs[1][0];

    // ============ T0 (buf0) ============
    rdA(as0, 0);
    rdB(bs0, 0, bR0);
    STA(0, kT1, 1);
    STA(1, kT1, 1);
    MID;
    cl(aR[0], bR0, 0);
    END;
    rdB(bs0, 1, bR1);
    STA(2, kT1, 1);
    STA(3, kT1, 1);
    MID;
    cl(aR[1], bR1, 0);
    END;
    rdA(as0, 1);
    if (more) {
      STB(0, kT2, 0);
      STB(1, kT2, 0);
    }
    MID;
    cl(aR[1], bR1, 1);
    END;
    if (more) {
      if constexpr (NC == 3) {
        STB(2, kT2, 0);
        STA(0, kT2, 0);
      } else {
        STA(0, kT2, 0);
        STA(1, kT2, 0);
      }
    }
    MID;
    cl(aR[0], bR0, 1);
    SB;
    if (more)
      asm volatile("s_waitcnt vmcnt(4)" ::: "memory");
    else
      asm volatile("s_waitcnt vmcnt(0)" ::: "memory");
    END;

    // ============ T1 (buf1) ============
    rdA(as1, 0);
    rdB(bs1, 0, bR0);
    if (more) {
      if constexpr (NC == 3) {
        STA(1, kT2, 0);
        STA(2, kT2, 0);
      } else {
        STA(2, kT2, 0);
        STA(3, kT2, 0);
      }
    }
    MID;
    cl(aR[0], bR0, 0);
    END;
    rdB(bs1, 1, bR1);
    if (more) {
      if constexpr (NC == 3) STA(3, kT2, 0);
    }
    MID;
    cl(aR[1], bR1, 0);
    END;
    rdA(as1, 1);
    if (more) {
      STB(0, kT3, 1);
      STB(1, kT3, 1);
    }
    MID;
    cl(aR[1], bR1, 1);
    END;
    if (more) {
      if constexpr (NC == 3) STB(2, kT3, 1);
    }
    MID;
    cl(aR[0], bR0, 1);
    SB;
    if (more) {
      if constexpr (NC == 3)
        asm volatile("s_waitcnt vmcnt(3)" ::: "memory");
      else
        asm volatile("s_waitcnt vmcnt(2)" ::: "memory");
    }
    END;
  }

  const int crow0 = bm + wm * 128;
  const int ccol0 = bn0 + wc * (NC * 16);
  if constexpr (F32OUT) {
    float* Cp = (float*)Cv;
#pragma unroll
    for (int r8 = 0; r8 < 8; r8++)
#pragma unroll
      for (int j = 0; j < NC; j++)
#pragma unroll
        for (int rr = 0; rr < 4; rr++) {
          int row = crow0 + (r8 >> 2) * 64 + (r8 & 3) * 16 + quad * 4 + rr;
          int col = ccol0 + j * 16 + l16;
          Cp[(size_t)row * ldc + col] = acc[r8][j][rr];
        }
  } else {
    u16* Cp = (u16*)Cv;
#pragma unroll
    for (int r8 = 0; r8 < 8; r8++)
#pragma unroll
      for (int j = 0; j < NC; j++)
#pragma unroll
        for (int rr = 0; rr < 4; rr++) {
          int row = crow0 + (r8 >> 2) * 64 + (r8 & 3) * 16 + quad * 4 + rr;
          int col = ccol0 + j * 16 + l16;
          Cp[(size_t)row * ldc + col] = f2bf(acc[r8][j][rr]);
        }
  }
#undef STA
#undef STB
#undef SB
#undef MID
#undef END
}

// ---------------------------------------------------------------------------
// In-place RoPE on Q (cols 0..4095) and K (cols 4096..5119) of qkv[2048][6144].
// ---------------------------------------------------------------------------
__global__ __launch_bounds__(256) void rope_k(u16* __restrict__ qkv,
                                              const float* __restrict__ fc,
                                              const float* __restrict__ fs) {
  int idx = blockIdx.x * 256 + threadIdx.x;
  int j = idx & 63;
  int rem = idx >> 6;
  int head = rem % 40;
  int s = rem / 40;
  float c = fc[s * 64 + j];
  float sn = fs[s * 64 + j];
  int col = (head < 32) ? (head * 128 + 2 * j) : (4096 + (head - 32) * 128 + 2 * j);
  u32* p = (u32*)&qkv[(size_t)s * 6144 + col];
  u32 v = *p;
  float e = bf2f((u16)(v & 0xFFFFu));
  float o = bf2f((u16)(v >> 16));
  float re = e * c - o * sn;
  float ro = e * sn + o * c;
  *p = (u32)f2bf(re) | ((u32)f2bf(ro) << 16);
}

// ---------------------------------------------------------------------------
// Sliding-window causal GQA attention, KVBLK=64, QBLK=256, 8 waves (512thr).
// grid = (32 heads, 8 q-blocks of 256) = 256 blocks = 1/CU.
// vs old (4 waves/32-k tiles): per-tile fixed costs (sync, staging, softmax
// setup) amortized 2x; per-wave window skip drops out-of-window tiles.
// Same verified math: unshifted softmax + analytic sliding-window mask,
// P via per-wave LDS roundtrip (b128-aligned stride 72), double-buffered
// K/V staging via gload_lds with involution swizzles:
//   K[64][128]: 16B chunk slot s at row r holds data slot s^(r&15)
//   V[128][64]: slot s at row r holds data slot s^(r&7)
// ---------------------------------------------------------------------------
__global__ __launch_bounds__(512) void attn_k(const u16* __restrict__ qkv,
                                              const u16* __restrict__ vt,
                                              u16* __restrict__ outb) {
  __shared__ __attribute__((aligned(16))) u16 Kb[2][64 * 128];
  __shared__ __attribute__((aligned(16))) u16 Vb[2][128 * 64];
  __shared__ __attribute__((aligned(16))) u16 plds[8][32 * 72];
  const int h = blockIdx.x;
  const int q0 = blockIdx.y * 256;
  const int t = threadIdx.x;
  const int wave = t >> 6;
  const int lane = t & 63;
  const int l16 = lane & 15;
  const int quad = lane >> 4;
  const int hkv = h >> 2;
  const int qw = q0 + wave * 32;
  u16* myp = &plds[wave][0];

  // Q fragments: 2 sets of 16 rows
  bf16x8 qa[2][4];
#pragma unroll
  for (int i = 0; i < 2; i++)
#pragma unroll
    for (int kc = 0; kc < 4; kc++)
      qa[i][kc] = *(const bf16x8*)&qkv[(size_t)(qw + i * 16 + l16) * 6144 +
                                       h * 128 + kc * 32 + quad * 8];

  f32x4 o[2][8];
#pragma unroll
  for (int i = 0; i < 2; i++)
#pragma unroll
    for (int d = 0; d < 8; d++) o[i][d] = (f32x4){0.f, 0.f, 0.f, 0.f};
  float lloc[2][4] = {{0.f, 0.f, 0.f, 0.f}, {0.f, 0.f, 0.f, 0.f}};

  const int kb_start = (q0 - 1023 > 0 ? q0 - 1023 : 0) & ~63;
  const int kb_last = q0 + 192;  // (q0+255) & ~63
  const float sc = 0.08838834764831845f;  // 1/sqrt(128)

  // staging indices (512 threads, 2 chunks each per buffer)
  const int kr0 = t >> 4, ks0 = t & 15;
  const int kr1 = (512 + t) >> 4, ks1 = t & 15;
  const int vr0 = t >> 3, vs0 = t & 7;
  const int vr1 = (512 + t) >> 3, vs1 = t & 7;
  const u16* kg = qkv + 4096 + hkv * 128;
  const u16* vg = vt + (size_t)hkv * 128 * 2048;

#define STAGE(kb_, nb_)                                                       \
  do {                                                                        \
    int kb__ = (kb_);                                                         \
    gload_lds16(&kg[(size_t)(kb__ + kr0) * 6144 + (ks0 ^ (kr0 & 15)) * 8],    \
                &Kb[nb_][t * 8]);                                             \
    gload_lds16(&kg[(size_t)(kb__ + kr1) * 6144 + (ks1 ^ (kr1 & 15)) * 8],    \
                &Kb[nb_][4096 + t * 8]);                                      \
    gload_lds16(&vg[(size_t)vr0 * 2048 + kb__ + (vs0 ^ (vr0 & 7)) * 8],       \
                &Vb[nb_][t * 8]);                                             \
    gload_lds16(&vg[(size_t)vr1 * 2048 + kb__ + (vs1 ^ (vr1 & 7)) * 8],       \
                &Vb[nb_][4096 + t * 8]);                                      \
  } while (0)

  STAGE(kb_start, 0);
  int cur = 0;

  for (int kb = kb_start; kb <= kb_last; kb += 64) {
    __syncthreads();  // buf[cur] staged (drains vmcnt); prev reads done
    if (kb + 64 <= kb_last) STAGE(kb + 64, cur ^ 1);
    // per-wave window skip: tile fully below diagonal or fully out of window
    if (kb > qw + 31 || kb + 1087 <= qw) {
      cur ^= 1;
      continue;
    }
    const u16* kcur = &Kb[cur][0];
    const u16* vcur = &Vb[cur][0];

    // ---- QK^T: 32q x 64k ----
    f32x4 s[2][4];
#pragma unroll
    for (int i = 0; i < 2; i++)
#pragma unroll
      for (int kt = 0; kt < 4; kt++) s[i][kt] = (f32x4){0.f, 0.f, 0.f, 0.f};
#pragma unroll
    for (int kc = 0; kc < 4; kc++) {
      int ch = ((kc * 4 + quad) ^ l16) * 8;
      bf16x8 bfr[4];
#pragma unroll
      for (int kt = 0; kt < 4; kt++)
        bfr[kt] = *(const bf16x8*)&kcur[(kt * 16 + l16) * 128 + ch];
      __builtin_amdgcn_s_setprio(1);
#pragma unroll
      for (int kt = 0; kt < 4; kt++) {
        s[0][kt] = MFMA16(qa[0][kc], bfr[kt], s[0][kt]);
        s[1][kt] = MFMA16(qa[1][kc], bfr[kt], s[1][kt]);
      }
      __builtin_amdgcn_s_setprio(0);
    }

    // ---- unshifted softmax numerator + pack ----
    float p[2][4][4];
    bool fast = (kb + 63 <= qw) && (qw + 31 - kb <= 1023);
    if (fast) {
#pragma unroll
      for (int i = 0; i < 2; i++)
#pragma unroll
        for (int kt = 0; kt < 4; kt++)
#pragma unroll
          for (int r = 0; r < 4; r++) p[i][kt][r] = __expf(s[i][kt][r] * sc);
    } else {
#pragma unroll
      for (int i = 0; i < 2; i++)
#pragma unroll
        for (int kt = 0; kt < 4; kt++)
#pragma unroll
          for (int r = 0; r < 4; r++) {
            int row = qw + i * 16 + quad * 4 + r;
            int col = kb + kt * 16 + l16;
            bool v = (col <= row) && (row - col < 1024);
            p[i][kt][r] = v ? __expf(s[i][kt][r] * sc) : 0.f;
          }
    }
#pragma unroll
    for (int i = 0; i < 2; i++)
#pragma unroll
      for (int r = 0; r < 4; r++) {
        lloc[i][r] += (p[i][0][r] + p[i][1][r]) + (p[i][2][r] + p[i][3][r]);
#pragma unroll
        for (int kt = 0; kt < 4; kt++)
          myp[(i * 16 + quad * 4 + r) * 72 + kt * 16 + l16] =
              f2bf(p[i][kt][r]);
      }
    asm volatile("s_waitcnt lgkmcnt(0)" ::: "memory");
    __builtin_amdgcn_sched_barrier(0);
    bf16x8 pa[2][2];
#pragma unroll
    for (int i = 0; i < 2; i++)
#pragma unroll
      for (int kh = 0; kh < 2; kh++)
        pa[i][kh] = *(const bf16x8*)&myp[(i * 16 + l16) * 72 + kh * 32 +
                                         quad * 8];
    // ---- PV: V fragments read once, shared by both q-sets ----
#pragma unroll
    for (int kh = 0; kh < 2; kh++) {
#pragma unroll
      for (int d = 0; d < 8; d++) {
        int rv = l16 + 16 * d;
        bf16x8 vb = *(const bf16x8*)
            &vcur[rv * 64 + (((kh * 4 + quad) ^ (rv & 7)) * 8)];
        o[0][d] = MFMA16(pa[0][kh], vb, o[0][d]);
        o[1][d] = MFMA16(pa[1][kh], vb, o[1][d]);
      }
    }
    cur ^= 1;
  }

  // ---- final row-sum reduce + divide + store ----
#pragma unroll
  for (int i = 0; i < 2; i++) {
    float inv[4];
#pragma unroll
    for (int r = 0; r < 4; r++) {
      float l = lloc[i][r];
#pragma unroll
      for (int m = 8; m >= 1; m >>= 1) l += __shfl_xor(l, m, 64);
      inv[r] = 1.0f / l;
    }
#pragma unroll
    for (int d = 0; d < 8; d++)
#pragma unroll
      for (int r = 0; r < 4; r++) {
        int row = qw + i * 16 + quad * 4 + r;
        outb[(size_t)row * 4096 + h * 128 + d * 16 + l16] =
            f2bf(o[i][d][r] * inv[r]);
      }
  }
#undef STAGE
}

// ---------------------------------------------------------------------------
// Workspace layout (bytes):
//   0         : xb    [2048][4096] bf16 (16777216)
//   16777216  : wqkvT [6144][4096] bf16 (50331648)  (wq rows 0..4095,
//               wk rows 4096..5119, wv rows 5120..6143; contiguous)
//               -- reused for woT [4096][4096] after GEMM1
//   67108864  : qkvb  [2048][6144] bf16 (25165824)
//   92274688  : vtb   [1024][2048] bf16 ( 4194304)
//   96468992  : aout  [2048][4096] bf16 (16777216)
// ---------------------------------------------------------------------------
extern "C" void kernel_launch(void* const* d_in, const int* in_sizes, int n_in,
                              void* d_out, int out_size, void* d_ws, size_t ws_size,
                              hipStream_t stream) {
  const float* x = (const float*)d_in[0];
  const float* fc = (const float*)d_in[1];
  const float* fs = (const float*)d_in[2];
  // d_in[3] = mask (unused; recomputed analytically)
  const float* wq = (const float*)d_in[4];
  const float* wk = (const float*)d_in[5];
  const float* wv = (const float*)d_in[6];
  const float* wo = (const float*)d_in[7];
  float* outp = (float*)d_out;
  char* ws = (char*)d_ws;
  u16* xb = (u16*)(ws);
  u16* wqkvT = (u16*)(ws + 16777216);
  u16* qkvb = (u16*)(ws + 67108864);
  u16* vtb = (u16*)(ws + 92274688);
  u16* aout = (u16*)(ws + 96468992);

  cvt_x<<<8192, 256, 0, stream>>>(x, xb);
  tbf_f2b<<<dim3(64, 64), 256, 0, stream>>>(wq, wqkvT, 4096, 4096);
  tbf_f2b<<<dim3(16, 64), 256, 0, stream>>>(wk, wqkvT + (size_t)4096 * 4096,
                                            1024, 4096);
  tbf_f2b<<<dim3(16, 64), 256, 0, stream>>>(wv, wqkvT + (size_t)5120 * 4096,
                                            1024, 4096);
  gemm8<192, 0><<<256, 512, 0, stream>>>(xb, wqkvT, qkvb, 4096, 6144);
  rope_k<<<20480, 256, 0, stream>>>(qkvb, fc, fs);
  tbf_b<<<dim3(16, 32), 256, 0, stream>>>(qkvb + 5120, vtb, 6144, 2048);
  tbf_f2b<<<dim3(64, 64), 256, 0, stream>>>(wo, wqkvT, 4096, 4096);
  attn_k<<<dim3(32, 8), 512, 0, stream>>>(qkvb, vtb, aout);
  gemm8<128, 1><<<256, 512, 0, stream>>>(aout, wqkvT, outp, 4096, 4096);
}